// Round 2
// baseline (1094.085 us; speedup 1.0000x reference)
//
#include <hip/hip_runtime.h>
#include <math.h>

#define TPB 256
#define SCANT 1024

namespace {

constexpr int IN_FEAT = 512;
constexpr int HID = 16;

__device__ inline float4 shfl_xor4(float4 v, int m) {
  v.x = __shfl_xor(v.x, m);
  v.y = __shfl_xor(v.y, m);
  v.z = __shfl_xor(v.z, m);
  v.w = __shfl_xor(v.w, m);
  return v;
}

// ---- edge dtype detect: int64 (all high words zero) vs int32 ----
__global__ void k_detect(const int* __restrict__ ei32, int* __restrict__ flag) {
  __shared__ int red[TPB];
  int t = threadIdx.x;
  int v = 0;
  for (int i = t; i < 2048; i += TPB) v |= ei32[2 * i + 1];
  red[t] = v;
  __syncthreads();
  for (int s = TPB / 2; s > 0; s >>= 1) {
    if (t < s) red[t] |= red[t + s];
    __syncthreads();
  }
  if (t == 0) *flag = (red[0] == 0) ? 1 : 0;  // 1 => int64 layout
}

__global__ void k_zero_i(int* __restrict__ p, int n) {
  int i = blockIdx.x * TPB + threadIdx.x;
  if (i < n) p[i] = 0;
}

// ---- in-degree histogram (int) into cnt ----
__global__ void k_hist(const int* __restrict__ ei32, const long long* __restrict__ ei64,
                       const int* __restrict__ flag, int* __restrict__ cnt, int E) {
  int e = blockIdx.x * TPB + threadIdx.x;
  if (e >= E) return;
  int d = (*flag) ? (int)ei64[(long long)E + e] : ei32[(long long)E + e];
  atomicAdd(&cnt[d], 1);
}

// ---- single-block exclusive scan: cnt_cursor holds counts in, cursors out.
//      offsets[i] = exclusive prefix; offsets[n] = E; dinv[i] = rsqrt(cnt+1). ----
__global__ __launch_bounds__(SCANT) void k_scan(int* __restrict__ cnt_cursor,
                                                int* __restrict__ offsets,
                                                float* __restrict__ dinv, int n) {
  __shared__ int sb[SCANT];
  int t = threadIdx.x;
  int chunk = (n + SCANT - 1) / SCANT;
  int lo = t * chunk;
  int hi = lo + chunk;
  if (lo > n) lo = n;
  if (hi > n) hi = n;
  int s = 0;
  for (int i = lo; i < hi; i++) s += cnt_cursor[i];
  sb[t] = s;
  __syncthreads();
  for (int off = 1; off < SCANT; off <<= 1) {
    int v = (t >= off) ? sb[t - off] : 0;
    __syncthreads();
    sb[t] += v;
    __syncthreads();
  }
  int run = sb[t] - s;  // exclusive prefix of this thread's chunk
  for (int i = lo; i < hi; i++) {
    int c = cnt_cursor[i];
    offsets[i] = run;
    cnt_cursor[i] = run;  // becomes the build cursor
    dinv[i] = rsqrtf((float)(c + 1));
    run += c;
  }
  if (hi == n && lo < n) offsets[n] = run;
}

// ---- CSR build: counting-sort srcs by dst ----
__global__ void k_build(const int* __restrict__ ei32, const long long* __restrict__ ei64,
                        const int* __restrict__ flag, int* __restrict__ cursor,
                        int* __restrict__ csr, int E) {
  int e = blockIdx.x * TPB + threadIdx.x;
  if (e >= E) return;
  int s, d;
  if (*flag) {
    s = (int)ei64[e];
    d = (int)ei64[(long long)E + e];
  } else {
    s = ei32[e];
    d = ei32[(long long)E + e];
  }
  int pos = atomicAdd(&cursor[d], 1);
  csr[pos] = s;
}

// ---- layer1 GEMM v2: hs1 = (x @ W1) * dinv[row]
//      BM=192 rows/block, BK=64, 3 rows x 4 cols per thread (register blocked).
//      xs chunk-swizzled (kk ^ (rr&15)) -> 2-way max bank aliasing on reads. ----
__global__ __launch_bounds__(TPB) void k_gemm1b(const float* __restrict__ x,
                                                const float* __restrict__ W1,
                                                const float* __restrict__ dinv,
                                                float* __restrict__ hs1, int n) {
  __shared__ float xs[192 * 64];  // [rr][kk^(rr&15)] in float4 chunks (48 KB)
  __shared__ float wt[16 * 68];   // wt[c][kf] at c*68+kf (4.25 KB, pad row 68)
  int t = threadIdx.x;
  int rq = t >> 2;  // 0..63
  int cq = t & 3;   // 0..3
  int R0 = blockIdx.x * 192;
  float acc[3][4];
#pragma unroll
  for (int i = 0; i < 3; i++)
#pragma unroll
    for (int c = 0; c < 4; c++) acc[i][c] = 0.f;

  const float4* x4 = (const float4*)x;
  for (int tile = 0; tile < 8; tile++) {
    int k04 = tile << 4;  // float4 index base within a row
    // stage x: 192 rows x 16 chunks = 3072 float4, 12/thread, coalesced
#pragma unroll
    for (int p = 0; p < 12; p++) {
      int i = p * TPB + t;
      int rr = i >> 4, kk = i & 15;
      int row = R0 + rr;
      if (row > n - 1) row = n - 1;
      float4 v = x4[(long long)row * 128 + k04 + kk];
      *(float4*)&xs[((rr << 4) + (kk ^ (rr & 15))) << 2] = v;
    }
    // stage W tile: wt[c][kf] = W1[(k0+kf)*16 + c] (coalesced reads)
#pragma unroll
    for (int p = 0; p < 4; p++) {
      int i = p * TPB + t;
      int c = i & 15, kf = i >> 4;  // kf 0..63
      wt[c * 68 + kf] = W1[(((tile << 6) + kf) << 4) + c];
    }
    __syncthreads();
#pragma unroll 4
    for (int kk = 0; kk < 16; kk++) {
      float4 wv[4];
#pragma unroll
      for (int c = 0; c < 4; c++)
        wv[c] = *(const float4*)&wt[(cq * 4 + c) * 68 + (kk << 2)];
#pragma unroll
      for (int i = 0; i < 3; i++) {
        int rr = rq + (i << 6);
        float4 xv = *(const float4*)&xs[((rr << 4) + (kk ^ (rr & 15))) << 2];
#pragma unroll
        for (int c = 0; c < 4; c++) {
          acc[i][c] = fmaf(xv.x, wv[c].x, acc[i][c]);
          acc[i][c] = fmaf(xv.y, wv[c].y, acc[i][c]);
          acc[i][c] = fmaf(xv.z, wv[c].z, acc[i][c]);
          acc[i][c] = fmaf(xv.w, wv[c].w, acc[i][c]);
        }
      }
    }
    __syncthreads();
  }
#pragma unroll
  for (int i = 0; i < 3; i++) {
    int row = R0 + rq + (i << 6);
    if (row < n) {
      float di = dinv[row];
      float4 o = make_float4(acc[i][0] * di, acc[i][1] * di, acc[i][2] * di,
                             acc[i][3] * di);
      *(float4*)&hs1[(long long)row * HID + (cq << 2)] = o;
    }
  }
}

// ---- layer1 GEMM (legacy, fallback path): hs1 = (x @ W1) * dinv; t1 init ----
__global__ __launch_bounds__(TPB) void k_gemm1(const float* __restrict__ x,
                                               const float* __restrict__ W1,
                                               const float* __restrict__ dinv,
                                               float* __restrict__ hs1,
                                               float* __restrict__ t1, int n) {
  __shared__ float Wt[HID * IN_FEAT];  // [c][k], chunk (k>>2) xor (c&7)
  __shared__ float xsl[16 * IN_FEAT];  // [r][k], chunk (k>>2) xor (r&7)
  int t = threadIdx.x;
  for (int i = t; i < IN_FEAT * HID; i += TPB) {
    int k = i >> 4, c = i & 15;
    int pk = (k >> 2) ^ (c & 7);
    Wt[c * IN_FEAT + (pk << 2) + (k & 3)] = W1[i];
  }
  int c = t >> 4, r = t & 15;
  int xsw = r & 7, wsw = c & 7;
  int ntiles = (n + 15) >> 4;
  for (int tile = blockIdx.x; tile < ntiles; tile += gridDim.x) {
    int r0 = tile << 4;
    for (int i = t; i < 16 * (IN_FEAT / 4); i += TPB) {
      int rr = i >> 7, kk = i & 127;
      int row = r0 + rr;
      if (row > n - 1) row = n - 1;
      float4 v = ((const float4*)x)[(long long)row * (IN_FEAT / 4) + kk];
      *(float4*)&xsl[rr * IN_FEAT + ((kk ^ (rr & 7)) << 2)] = v;
    }
    __syncthreads();
    float acc = 0.f;
#pragma unroll 8
    for (int kk = 0; kk < IN_FEAT / 4; kk++) {
      float4 xv = *(const float4*)&xsl[r * IN_FEAT + ((kk ^ xsw) << 2)];
      float4 wv = *(const float4*)&Wt[c * IN_FEAT + ((kk ^ wsw) << 2)];
      acc = fmaf(xv.x, wv.x, acc);
      acc = fmaf(xv.y, wv.y, acc);
      acc = fmaf(xv.z, wv.z, acc);
      acc = fmaf(xv.w, wv.w, acc);
    }
    int row = r0 + r;
    if (row < n) {
      float val = acc * dinv[row];
      hs1[(long long)row * HID + c] = val;
      if (t1) t1[(long long)row * HID + c] = val;
    }
    __syncthreads();
  }
}

// ---- layer1 aggregation: wave per node, float4 gather over CSR, no atomics ----
__global__ void k_agg1(const int* __restrict__ offsets, const int* __restrict__ csr,
                       const float* __restrict__ hs1, float* __restrict__ t1, int n) {
  int wid = (int)(((unsigned)blockIdx.x * TPB + threadIdx.x) >> 6);
  if (wid >= n) return;
  int lane = threadIdx.x & 63;
  int q = lane & 3;    // float4 slot (4 feats)
  int eg = lane >> 2;  // 16 edge groups
  int s0 = offsets[wid], s1 = offsets[wid + 1];
  float4 acc = make_float4(0.f, 0.f, 0.f, 0.f);
  for (int e = s0 + eg; e < s1; e += 16) {
    int s = csr[e];
    float4 v = *(const float4*)(hs1 + (long long)s * HID + (q << 2));
    acc.x += v.x; acc.y += v.y; acc.z += v.z; acc.w += v.w;
  }
  for (int m = 4; m < 64; m <<= 1) {
    float4 o = shfl_xor4(acc, m);
    acc.x += o.x; acc.y += o.y; acc.z += o.z; acc.w += o.w;
  }
  if (lane < 4) {
    float4 sv = *(const float4*)(hs1 + (long long)wid * HID + (lane << 2));  // self-loop
    acc.x += sv.x; acc.y += sv.y; acc.z += sv.z; acc.w += sv.w;
    *(float4*)(t1 + (long long)wid * HID + (lane << 2)) = acc;
  }
}

// ---- layer1 epilogue + layer2 GEMM: h1 = relu(dinv*t1 + b1); hs2 = (h1@W2)*dinv ----
__global__ void k_layer2(const float* __restrict__ t1, const float* __restrict__ dinv,
                         const float* __restrict__ b1, const float* __restrict__ W2,
                         float* __restrict__ hs2, float* __restrict__ t2, int n) {
  int i = blockIdx.x * TPB + threadIdx.x;
  if (i >= n) return;
  float di = dinv[i];
  float h[16];
  const float4* tp = (const float4*)(t1 + (long long)i * 16);
#pragma unroll
  for (int q = 0; q < 4; q++) {
    float4 v = tp[q];
    float4 b = ((const float4*)b1)[q];
    h[4 * q + 0] = fmaxf(fmaf(di, v.x, b.x), 0.f);
    h[4 * q + 1] = fmaxf(fmaf(di, v.y, b.y), 0.f);
    h[4 * q + 2] = fmaxf(fmaf(di, v.z, b.z), 0.f);
    h[4 * q + 3] = fmaxf(fmaf(di, v.w, b.w), 0.f);
  }
  float o[8];
#pragma unroll
  for (int j = 0; j < 7; j++) {
    float s = 0.f;
#pragma unroll
    for (int cc = 0; cc < 16; cc++) s = fmaf(h[cc], W2[cc * 7 + j], s);
    o[j] = s * di;
  }
  o[7] = 0.f;
  float4 lo = make_float4(o[0], o[1], o[2], o[3]);
  float4 hi = make_float4(o[4], o[5], o[6], o[7]);
  float4* hp = (float4*)(hs2 + (long long)i * 8);
  hp[0] = lo; hp[1] = hi;
  if (t2) {
    float4* qp = (float4*)(t2 + (long long)i * 8);
    qp[0] = lo; qp[1] = hi;
  }
}

// ---- layer2 aggregation + bias + log_softmax fused: wave per node ----
__global__ void k_agg2(const int* __restrict__ offsets, const int* __restrict__ csr,
                       const float* __restrict__ hs2, const float* __restrict__ dinv,
                       const float* __restrict__ b2, float* __restrict__ out, int n) {
  int wid = (int)(((unsigned)blockIdx.x * TPB + threadIdx.x) >> 6);
  if (wid >= n) return;
  int lane = threadIdx.x & 63;
  int q = lane & 1;    // which float4 half (feats 0-3 / 4-7)
  int eg = lane >> 1;  // 32 edge groups
  int s0 = offsets[wid], s1 = offsets[wid + 1];
  float4 acc = make_float4(0.f, 0.f, 0.f, 0.f);
  for (int e = s0 + eg; e < s1; e += 32) {
    int s = csr[e];
    float4 v = *(const float4*)(hs2 + (long long)s * 8 + (q << 2));
    acc.x += v.x; acc.y += v.y; acc.z += v.z; acc.w += v.w;
  }
  for (int m = 2; m < 64; m <<= 1) {
    float4 o = shfl_xor4(acc, m);
    acc.x += o.x; acc.y += o.y; acc.z += o.z; acc.w += o.w;
  }
  float4 sv = *(const float4*)(hs2 + (long long)wid * 8 + (q << 2));  // self-loop
  acc.x += sv.x; acc.y += sv.y; acc.z += sv.z; acc.w += sv.w;
  float di = dinv[wid];
  int f0 = q << 2;
  float vx = fmaf(di, acc.x, b2[f0 + 0]);
  float vy = fmaf(di, acc.y, b2[f0 + 1]);
  float vz = fmaf(di, acc.z, b2[f0 + 2]);
  float vw = (q == 0) ? fmaf(di, acc.w, b2[3]) : 0.f;  // f==7 invalid
  float vw_eff = (q == 0) ? vw : -1e30f;
  float mloc = fmaxf(fmaxf(vx, vy), fmaxf(vz, vw_eff));
  float mm = fmaxf(mloc, __shfl_xor(mloc, 1));
  float sl = expf(vx - mm) + expf(vy - mm) + expf(vz - mm) +
             ((q == 0) ? expf(vw - mm) : 0.f);
  float ss = sl + __shfl_xor(sl, 1);
  float lse = mm + logf(ss);
  if (lane < 2) {
    long long base = (long long)wid * 7 + (q << 2);
    out[base + 0] = vx - lse;
    out[base + 1] = vy - lse;
    out[base + 2] = vz - lse;
    if (q == 0) out[base + 3] = vw - lse;
  }
}

// ================= fallback path (atomic scatter; previous verified kernel) =========
__global__ void k_deg_init(float* __restrict__ deg, int n) {
  int i = blockIdx.x * TPB + threadIdx.x;
  if (i < n) deg[i] = 1.0f;
}

__global__ void k_deg_accum(const int* __restrict__ ei32, const long long* __restrict__ ei64,
                            const int* __restrict__ flag, float* __restrict__ deg, int E) {
  int e = blockIdx.x * TPB + threadIdx.x;
  if (e >= E) return;
  int d = (*flag) ? (int)ei64[(long long)E + e] : ei32[(long long)E + e];
  atomicAdd(&deg[d], 1.0f);
}

__global__ void k_rsqrt(float* __restrict__ deg, int n) {
  int i = blockIdx.x * TPB + threadIdx.x;
  if (i < n) deg[i] = rsqrtf(deg[i]);
}

__global__ void k_scatter1(const int* __restrict__ ei32, const long long* __restrict__ ei64,
                           const int* __restrict__ flag, const float* __restrict__ hs1,
                           float* __restrict__ t1, int E) {
  long long gid = (long long)blockIdx.x * TPB + threadIdx.x;
  long long e = gid >> 4;
  if (e >= E) return;
  int f = (int)(gid & 15);
  int s, d;
  if (*flag) {
    s = (int)ei64[e];
    d = (int)ei64[E + e];
  } else {
    s = ei32[e];
    d = ei32[(long long)E + e];
  }
  atomicAdd(&t1[(long long)d * HID + f], hs1[(long long)s * HID + f]);
}

__global__ void k_scatter2(const int* __restrict__ ei32, const long long* __restrict__ ei64,
                           const int* __restrict__ flag, const float* __restrict__ hs2,
                           float* __restrict__ t2, int E) {
  long long gid = (long long)blockIdx.x * TPB + threadIdx.x;
  long long e = gid >> 3;
  if (e >= E) return;
  int f = (int)(gid & 7);
  if (f == 7) return;
  int s, d;
  if (*flag) {
    s = (int)ei64[e];
    d = (int)ei64[E + e];
  } else {
    s = ei32[e];
    d = ei32[(long long)E + e];
  }
  atomicAdd(&t2[(long long)d * 8 + f], hs2[(long long)s * 8 + f]);
}

__global__ void k_final(const float* __restrict__ t2, const float* __restrict__ dinv,
                        const float* __restrict__ b2, float* __restrict__ out, int n) {
  int i = blockIdx.x * TPB + threadIdx.x;
  if (i >= n) return;
  float di = dinv[i];
  float v[7];
  float m = -1e30f;
#pragma unroll
  for (int j = 0; j < 7; j++) {
    v[j] = fmaf(di, t2[(long long)i * 8 + j], b2[j]);
    m = fmaxf(m, v[j]);
  }
  float s = 0.f;
#pragma unroll
  for (int j = 0; j < 7; j++) s += expf(v[j] - m);
  float lse = m + logf(s);
#pragma unroll
  for (int j = 0; j < 7; j++) out[(long long)i * 7 + j] = v[j] - lse;
}

}  // namespace

extern "C" void kernel_launch(void* const* d_in, const int* in_sizes, int n_in,
                              void* d_out, int out_size, void* d_ws, size_t ws_size,
                              hipStream_t stream) {
  const float* x = (const float*)d_in[0];
  const int* ei32 = (const int*)d_in[1];
  const long long* ei64 = (const long long*)d_in[1];
  const float* W1 = (const float*)d_in[2];
  const float* b1 = (const float*)d_in[3];
  const float* W2 = (const float*)d_in[4];
  const float* b2 = (const float*)d_in[5];
  float* out = (float*)d_out;

  int n = in_sizes[0] / IN_FEAT;  // 100000
  int E = in_sizes[1] / 2;        // 3200000

  int nb_n = (n + TPB - 1) / TPB;
  int nb_e = (E + TPB - 1) / TPB;
  int nb_w = (n + 3) / 4;       // wave-per-node kernels: 4 waves/block
  int nb_g = (n + 191) / 192;   // gemm1b tiles

  float* ws = (float*)d_ws;
  int* flag = (int*)d_ws;

  // CSR-path workspace layout (16-word aligned regions)
  long long w = 64;
  auto align16 = [](long long v) { return (v + 15) & ~15LL; };
  float* dinv = ws + w; w = align16(w + n);
  int* offsets = (int*)(ws + w); w = align16(w + n + 1);
  int* cursor = (int*)(ws + w); w = align16(w + n);
  int* csr = (int*)(ws + w); w = align16(w + E);
  float* hs1 = ws + w; w = align16(w + (long long)n * HID);
  float* t1 = ws + w; w = align16(w + (long long)n * HID);
  float* hs2 = ws + w; w = align16(w + (long long)n * 8);
  bool csr_ok = (ws_size >= (size_t)w * 4);

  if (csr_ok) {
    hipLaunchKernelGGL(k_detect, dim3(1), dim3(TPB), 0, stream, ei32, flag);
    hipLaunchKernelGGL(k_zero_i, dim3(nb_n), dim3(TPB), 0, stream, cursor, n);
    hipLaunchKernelGGL(k_hist, dim3(nb_e), dim3(TPB), 0, stream, ei32, ei64, flag, cursor, E);
    hipLaunchKernelGGL(k_scan, dim3(1), dim3(SCANT), 0, stream, cursor, offsets, dinv, n);
    hipLaunchKernelGGL(k_build, dim3(nb_e), dim3(TPB), 0, stream, ei32, ei64, flag, cursor, csr, E);
    hipLaunchKernelGGL(k_gemm1b, dim3(nb_g), dim3(TPB), 0, stream, x, W1, dinv, hs1, n);
    hipLaunchKernelGGL(k_agg1, dim3(nb_w), dim3(TPB), 0, stream, offsets, csr, hs1, t1, n);
    hipLaunchKernelGGL(k_layer2, dim3(nb_n), dim3(TPB), 0, stream, t1, dinv, b1, W2, hs2,
                       (float*)nullptr, n);
    hipLaunchKernelGGL(k_agg2, dim3(nb_w), dim3(TPB), 0, stream, offsets, csr, hs2, dinv, b2,
                       out, n);
  } else {
    // previous verified atomic-scatter path
    float* dinv_f = ws + 64;
    float* hs1_f = dinv_f + n;
    float* t1_f = hs1_f + (long long)n * HID;
    float* hs2_f = t1_f + (long long)n * HID;
    float* t2_f = hs2_f + (long long)n * 8;
    long long w1 = (long long)E * 16, w2 = (long long)E * 8;
    int nb_s1 = (int)((w1 + TPB - 1) / TPB);
    int nb_s2 = (int)((w2 + TPB - 1) / TPB);
    hipLaunchKernelGGL(k_detect, dim3(1), dim3(TPB), 0, stream, ei32, flag);
    hipLaunchKernelGGL(k_deg_init, dim3(nb_n), dim3(TPB), 0, stream, dinv_f, n);
    hipLaunchKernelGGL(k_deg_accum, dim3(nb_e), dim3(TPB), 0, stream, ei32, ei64, flag, dinv_f, E);
    hipLaunchKernelGGL(k_rsqrt, dim3(nb_n), dim3(TPB), 0, stream, dinv_f, n);
    hipLaunchKernelGGL(k_gemm1, dim3(1024), dim3(TPB), 0, stream, x, W1, dinv_f, hs1_f, t1_f, n);
    hipLaunchKernelGGL(k_scatter1, dim3(nb_s1), dim3(TPB), 0, stream, ei32, ei64, flag, hs1_f, t1_f, E);
    hipLaunchKernelGGL(k_layer2, dim3(nb_n), dim3(TPB), 0, stream, t1_f, dinv_f, b1, W2, hs2_f, t2_f, n);
    hipLaunchKernelGGL(k_scatter2, dim3(nb_s2), dim3(TPB), 0, stream, ei32, ei64, flag, hs2_f, t2_f, E);
    hipLaunchKernelGGL(k_final, dim3(nb_n), dim3(TPB), 0, stream, t2_f, dinv_f, b2, out, n);
  }
}

// Round 3
// 523.483 us; speedup vs baseline: 2.0900x; 2.0900x over previous
//
#include <hip/hip_runtime.h>
#include <math.h>

#define TPB 256
#define SCANT 1024

namespace {

constexpr int IN_FEAT = 512;
constexpr int HID = 16;

__device__ inline float4 shfl_xor4(float4 v, int m) {
  v.x = __shfl_xor(v.x, m);
  v.y = __shfl_xor(v.y, m);
  v.z = __shfl_xor(v.z, m);
  v.w = __shfl_xor(v.w, m);
  return v;
}

// ---- edge dtype detect: int64 (all high words zero) vs int32 ----
__global__ void k_detect(const int* __restrict__ ei32, int* __restrict__ flag) {
  __shared__ int red[TPB];
  int t = threadIdx.x;
  int v = 0;
  for (int i = t; i < 2048; i += TPB) v |= ei32[2 * i + 1];
  red[t] = v;
  __syncthreads();
  for (int s = TPB / 2; s > 0; s >>= 1) {
    if (t < s) red[t] |= red[t + s];
    __syncthreads();
  }
  if (t == 0) *flag = (red[0] == 0) ? 1 : 0;  // 1 => int64 layout
}

__global__ void k_zero_i(int* __restrict__ p, int n) {
  int i = blockIdx.x * TPB + threadIdx.x;
  if (i < n) p[i] = 0;
}

// ================= binned CSR build (bucket = dst>>8, 256 nodes/bucket) ==========
// Pass A: per-block LDS bucket histogram -> global bucketCnt (1 atomic/bucket/block)
__global__ __launch_bounds__(TPB) void k_binA(const int* __restrict__ ei32,
                                              const long long* __restrict__ ei64,
                                              const int* __restrict__ flag,
                                              int* __restrict__ bucketCnt, int E, int NB) {
  __shared__ int hist[1024];
  int t = threadIdx.x;
  for (int i = t; i < 1024; i += TPB) hist[i] = 0;
  __syncthreads();
  long long e0 = (long long)blockIdx.x * 8192;
  int use64 = *flag;
  for (int j = 0; j < 32; j++) {
    long long e = e0 + j * TPB + t;
    if (e < E) {
      int d = use64 ? (int)ei64[E + e] : ei32[E + e];
      atomicAdd(&hist[d >> 8], 1);
    }
  }
  __syncthreads();
  for (int b = t; b < NB; b += TPB) {
    int c = hist[b];
    if (c) atomicAdd(&bucketCnt[b], c);
  }
}

// Pass B: single-block scan of bucketCnt -> bucketBase[NB+1], cursor; offsets[n]=E
__global__ __launch_bounds__(SCANT) void k_binB(const int* __restrict__ bucketCnt,
                                                int* __restrict__ bucketBase,
                                                int* __restrict__ cursor,
                                                int* __restrict__ offsets, int n, int NB) {
  __shared__ int sb[SCANT];
  int t = threadIdx.x;
  int v = (t < NB) ? bucketCnt[t] : 0;
  sb[t] = v;
  __syncthreads();
  for (int off = 1; off < SCANT; off <<= 1) {
    int u = (t >= off) ? sb[t - off] : 0;
    __syncthreads();
    sb[t] += u;
    __syncthreads();
  }
  if (t < NB) {
    int base = sb[t] - v;
    bucketBase[t] = base;
    cursor[t] = base;
  }
  if (t == NB - 1) {
    bucketBase[NB] = sb[t];
    offsets[n] = sb[t];
  }
}

// Pass C: bin edges into contiguous bucket regions; writes are bump-allocated runs
// (~21 edges/bucket/block) of packed (local_dst<<24)|src, 4 B/edge.
__global__ __launch_bounds__(TPB) void k_binC(const int* __restrict__ ei32,
                                              const long long* __restrict__ ei64,
                                              const int* __restrict__ flag,
                                              int* __restrict__ cursor,
                                              unsigned int* __restrict__ binned, int E, int NB) {
  __shared__ int cnt[1024];
  __shared__ int gbase[1024];
  int t = threadIdx.x;
  for (int i = t; i < 1024; i += TPB) cnt[i] = 0;
  __syncthreads();
  long long e0 = (long long)blockIdx.x * 8192;
  int use64 = *flag;
  for (int j = 0; j < 32; j++) {
    long long e = e0 + j * TPB + t;
    if (e < E) {
      int d = use64 ? (int)ei64[E + e] : ei32[E + e];
      atomicAdd(&cnt[d >> 8], 1);
    }
  }
  __syncthreads();
  for (int b = t; b < NB; b += TPB) {
    int c = cnt[b];
    gbase[b] = c ? atomicAdd(&cursor[b], c) : 0;
  }
  __syncthreads();
  for (int i = t; i < 1024; i += TPB) cnt[i] = 0;  // becomes local rank cursor
  __syncthreads();
  for (int j = 0; j < 32; j++) {
    long long e = e0 + j * TPB + t;
    if (e < E) {
      int s, d;
      if (use64) {
        s = (int)ei64[e];
        d = (int)ei64[E + e];
      } else {
        s = ei32[e];
        d = ei32[(long long)E + e];
      }
      int b = d >> 8;
      int r = atomicAdd(&cnt[b], 1);
      binned[gbase[b] + r] = ((unsigned)(d & 255) << 24) | (unsigned)s;
    }
  }
}

// Pass D: one block per bucket: per-node counts -> offsets, dinv, node-ordered csr.
// All global traffic coalesced; scatter confined to an L2-resident 32 KB window.
__global__ __launch_bounds__(TPB) void k_binD(const int* __restrict__ bucketBase,
                                              const unsigned int* __restrict__ binned,
                                              int* __restrict__ offsets, float* __restrict__ dinv,
                                              int* __restrict__ csr, int n) {
  __shared__ int ncnt[256];
  __shared__ int nsc[256];
  __shared__ int ncur[256];
  int t = threadIdx.x;
  int b = blockIdx.x;
  int base = bucketBase[b];
  int cnt = bucketBase[b + 1] - base;
  ncnt[t] = 0;
  __syncthreads();
  for (int i = t; i < cnt; i += TPB) {
    unsigned p = binned[base + i];
    atomicAdd(&ncnt[p >> 24], 1);
  }
  __syncthreads();
  int c = ncnt[t];
  nsc[t] = c;
  __syncthreads();
  for (int off = 1; off < 256; off <<= 1) {
    int u = (t >= off) ? nsc[t - off] : 0;
    __syncthreads();
    nsc[t] += u;
    __syncthreads();
  }
  int excl = nsc[t] - c;
  int node = (b << 8) + t;
  if (node < n) {
    offsets[node] = base + excl;
    dinv[node] = rsqrtf((float)(c + 1));
  }
  ncur[t] = base + excl;
  __syncthreads();
  for (int i = t; i < cnt; i += TPB) {
    unsigned p = binned[base + i];
    int loc = (int)(p >> 24);
    int pos = atomicAdd(&ncur[loc], 1);
    csr[pos] = (int)(p & 0xFFFFFF);
  }
}

// ================= dense math kernels (verified round 2) =========================
// ---- layer1 GEMM v2: hs1 = (x @ W1) * dinv[row]; BM=192, 3x4 per thread ----
__global__ __launch_bounds__(TPB) void k_gemm1b(const float* __restrict__ x,
                                                const float* __restrict__ W1,
                                                const float* __restrict__ dinv,
                                                float* __restrict__ hs1, int n) {
  __shared__ float xs[192 * 64];  // [rr][kk^(rr&15)] float4 chunks (48 KB)
  __shared__ float wt[16 * 68];   // wt[c][kf] (4.25 KB, pad 68)
  int t = threadIdx.x;
  int rq = t >> 2;  // 0..63
  int cq = t & 3;   // 0..3
  int R0 = blockIdx.x * 192;
  float acc[3][4];
#pragma unroll
  for (int i = 0; i < 3; i++)
#pragma unroll
    for (int c = 0; c < 4; c++) acc[i][c] = 0.f;

  const float4* x4 = (const float4*)x;
  for (int tile = 0; tile < 8; tile++) {
    int k04 = tile << 4;
#pragma unroll
    for (int p = 0; p < 12; p++) {
      int i = p * TPB + t;
      int rr = i >> 4, kk = i & 15;
      int row = R0 + rr;
      if (row > n - 1) row = n - 1;
      float4 v = x4[(long long)row * 128 + k04 + kk];
      *(float4*)&xs[((rr << 4) + (kk ^ (rr & 15))) << 2] = v;
    }
#pragma unroll
    for (int p = 0; p < 4; p++) {
      int i = p * TPB + t;
      int c = i & 15, kf = i >> 4;
      wt[c * 68 + kf] = W1[(((tile << 6) + kf) << 4) + c];
    }
    __syncthreads();
#pragma unroll 4
    for (int kk = 0; kk < 16; kk++) {
      float4 wv[4];
#pragma unroll
      for (int c = 0; c < 4; c++)
        wv[c] = *(const float4*)&wt[(cq * 4 + c) * 68 + (kk << 2)];
#pragma unroll
      for (int i = 0; i < 3; i++) {
        int rr = rq + (i << 6);
        float4 xv = *(const float4*)&xs[((rr << 4) + (kk ^ (rr & 15))) << 2];
#pragma unroll
        for (int c = 0; c < 4; c++) {
          acc[i][c] = fmaf(xv.x, wv[c].x, acc[i][c]);
          acc[i][c] = fmaf(xv.y, wv[c].y, acc[i][c]);
          acc[i][c] = fmaf(xv.z, wv[c].z, acc[i][c]);
          acc[i][c] = fmaf(xv.w, wv[c].w, acc[i][c]);
        }
      }
    }
    __syncthreads();
  }
#pragma unroll
  for (int i = 0; i < 3; i++) {
    int row = R0 + rq + (i << 6);
    if (row < n) {
      float di = dinv[row];
      float4 o = make_float4(acc[i][0] * di, acc[i][1] * di, acc[i][2] * di,
                             acc[i][3] * di);
      *(float4*)&hs1[(long long)row * HID + (cq << 2)] = o;
    }
  }
}

// ---- layer1 aggregation: wave per node, float4 gather over CSR, no atomics ----
__global__ void k_agg1(const int* __restrict__ offsets, const int* __restrict__ csr,
                       const float* __restrict__ hs1, float* __restrict__ t1, int n) {
  int wid = (int)(((unsigned)blockIdx.x * TPB + threadIdx.x) >> 6);
  if (wid >= n) return;
  int lane = threadIdx.x & 63;
  int q = lane & 3;
  int eg = lane >> 2;
  int s0 = offsets[wid], s1 = offsets[wid + 1];
  float4 acc = make_float4(0.f, 0.f, 0.f, 0.f);
  for (int e = s0 + eg; e < s1; e += 16) {
    int s = csr[e];
    float4 v = *(const float4*)(hs1 + (long long)s * HID + (q << 2));
    acc.x += v.x; acc.y += v.y; acc.z += v.z; acc.w += v.w;
  }
  for (int m = 4; m < 64; m <<= 1) {
    float4 o = shfl_xor4(acc, m);
    acc.x += o.x; acc.y += o.y; acc.z += o.z; acc.w += o.w;
  }
  if (lane < 4) {
    float4 sv = *(const float4*)(hs1 + (long long)wid * HID + (lane << 2));
    acc.x += sv.x; acc.y += sv.y; acc.z += sv.z; acc.w += sv.w;
    *(float4*)(t1 + (long long)wid * HID + (lane << 2)) = acc;
  }
}

// ---- layer1 epilogue + layer2 GEMM ----
__global__ void k_layer2(const float* __restrict__ t1, const float* __restrict__ dinv,
                         const float* __restrict__ b1, const float* __restrict__ W2,
                         float* __restrict__ hs2, float* __restrict__ t2, int n) {
  int i = blockIdx.x * TPB + threadIdx.x;
  if (i >= n) return;
  float di = dinv[i];
  float h[16];
  const float4* tp = (const float4*)(t1 + (long long)i * 16);
#pragma unroll
  for (int q = 0; q < 4; q++) {
    float4 v = tp[q];
    float4 b = ((const float4*)b1)[q];
    h[4 * q + 0] = fmaxf(fmaf(di, v.x, b.x), 0.f);
    h[4 * q + 1] = fmaxf(fmaf(di, v.y, b.y), 0.f);
    h[4 * q + 2] = fmaxf(fmaf(di, v.z, b.z), 0.f);
    h[4 * q + 3] = fmaxf(fmaf(di, v.w, b.w), 0.f);
  }
  float o[8];
#pragma unroll
  for (int j = 0; j < 7; j++) {
    float s = 0.f;
#pragma unroll
    for (int cc = 0; cc < 16; cc++) s = fmaf(h[cc], W2[cc * 7 + j], s);
    o[j] = s * di;
  }
  o[7] = 0.f;
  float4 lo = make_float4(o[0], o[1], o[2], o[3]);
  float4 hi = make_float4(o[4], o[5], o[6], o[7]);
  float4* hp = (float4*)(hs2 + (long long)i * 8);
  hp[0] = lo; hp[1] = hi;
  if (t2) {
    float4* qp = (float4*)(t2 + (long long)i * 8);
    qp[0] = lo; qp[1] = hi;
  }
}

// ---- layer2 aggregation + bias + log_softmax fused ----
__global__ void k_agg2(const int* __restrict__ offsets, const int* __restrict__ csr,
                       const float* __restrict__ hs2, const float* __restrict__ dinv,
                       const float* __restrict__ b2, float* __restrict__ out, int n) {
  int wid = (int)(((unsigned)blockIdx.x * TPB + threadIdx.x) >> 6);
  if (wid >= n) return;
  int lane = threadIdx.x & 63;
  int q = lane & 1;
  int eg = lane >> 1;
  int s0 = offsets[wid], s1 = offsets[wid + 1];
  float4 acc = make_float4(0.f, 0.f, 0.f, 0.f);
  for (int e = s0 + eg; e < s1; e += 32) {
    int s = csr[e];
    float4 v = *(const float4*)(hs2 + (long long)s * 8 + (q << 2));
    acc.x += v.x; acc.y += v.y; acc.z += v.z; acc.w += v.w;
  }
  for (int m = 2; m < 64; m <<= 1) {
    float4 o = shfl_xor4(acc, m);
    acc.x += o.x; acc.y += o.y; acc.z += o.z; acc.w += o.w;
  }
  float4 sv = *(const float4*)(hs2 + (long long)wid * 8 + (q << 2));
  acc.x += sv.x; acc.y += sv.y; acc.z += sv.z; acc.w += sv.w;
  float di = dinv[wid];
  int f0 = q << 2;
  float vx = fmaf(di, acc.x, b2[f0 + 0]);
  float vy = fmaf(di, acc.y, b2[f0 + 1]);
  float vz = fmaf(di, acc.z, b2[f0 + 2]);
  float vw = (q == 0) ? fmaf(di, acc.w, b2[3]) : 0.f;
  float vw_eff = (q == 0) ? vw : -1e30f;
  float mloc = fmaxf(fmaxf(vx, vy), fmaxf(vz, vw_eff));
  float mm = fmaxf(mloc, __shfl_xor(mloc, 1));
  float sl = expf(vx - mm) + expf(vy - mm) + expf(vz - mm) +
             ((q == 0) ? expf(vw - mm) : 0.f);
  float ss = sl + __shfl_xor(sl, 1);
  float lse = mm + logf(ss);
  if (lane < 2) {
    long long base = (long long)wid * 7 + (q << 2);
    out[base + 0] = vx - lse;
    out[base + 1] = vy - lse;
    out[base + 2] = vz - lse;
    if (q == 0) out[base + 3] = vw - lse;
  }
}

// ================= legacy CSR-build kernels (fallback #1) ========================
__global__ void k_hist(const int* __restrict__ ei32, const long long* __restrict__ ei64,
                       const int* __restrict__ flag, int* __restrict__ cnt, int E) {
  int e = blockIdx.x * TPB + threadIdx.x;
  if (e >= E) return;
  int d = (*flag) ? (int)ei64[(long long)E + e] : ei32[(long long)E + e];
  atomicAdd(&cnt[d], 1);
}

__global__ __launch_bounds__(SCANT) void k_scan(int* __restrict__ cnt_cursor,
                                                int* __restrict__ offsets,
                                                float* __restrict__ dinv, int n) {
  __shared__ int sb[SCANT];
  int t = threadIdx.x;
  int chunk = (n + SCANT - 1) / SCANT;
  int lo = t * chunk;
  int hi = lo + chunk;
  if (lo > n) lo = n;
  if (hi > n) hi = n;
  int s = 0;
  for (int i = lo; i < hi; i++) s += cnt_cursor[i];
  sb[t] = s;
  __syncthreads();
  for (int off = 1; off < SCANT; off <<= 1) {
    int v = (t >= off) ? sb[t - off] : 0;
    __syncthreads();
    sb[t] += v;
    __syncthreads();
  }
  int run = sb[t] - s;
  for (int i = lo; i < hi; i++) {
    int c = cnt_cursor[i];
    offsets[i] = run;
    cnt_cursor[i] = run;
    dinv[i] = rsqrtf((float)(c + 1));
    run += c;
  }
  if (hi == n && lo < n) offsets[n] = run;
}

__global__ void k_build(const int* __restrict__ ei32, const long long* __restrict__ ei64,
                        const int* __restrict__ flag, int* __restrict__ cursor,
                        int* __restrict__ csr, int E) {
  int e = blockIdx.x * TPB + threadIdx.x;
  if (e >= E) return;
  int s, d;
  if (*flag) {
    s = (int)ei64[e];
    d = (int)ei64[(long long)E + e];
  } else {
    s = ei32[e];
    d = ei32[(long long)E + e];
  }
  int pos = atomicAdd(&cursor[d], 1);
  csr[pos] = s;
}

// ================= atomic-scatter kernels (fallback #2) ==========================
__global__ __launch_bounds__(TPB) void k_gemm1(const float* __restrict__ x,
                                               const float* __restrict__ W1,
                                               const float* __restrict__ dinv,
                                               float* __restrict__ hs1,
                                               float* __restrict__ t1, int n) {
  __shared__ float Wt[HID * IN_FEAT];
  __shared__ float xsl[16 * IN_FEAT];
  int t = threadIdx.x;
  for (int i = t; i < IN_FEAT * HID; i += TPB) {
    int k = i >> 4, c = i & 15;
    int pk = (k >> 2) ^ (c & 7);
    Wt[c * IN_FEAT + (pk << 2) + (k & 3)] = W1[i];
  }
  int c = t >> 4, r = t & 15;
  int xsw = r & 7, wsw = c & 7;
  int ntiles = (n + 15) >> 4;
  for (int tile = blockIdx.x; tile < ntiles; tile += gridDim.x) {
    int r0 = tile << 4;
    for (int i = t; i < 16 * (IN_FEAT / 4); i += TPB) {
      int rr = i >> 7, kk = i & 127;
      int row = r0 + rr;
      if (row > n - 1) row = n - 1;
      float4 v = ((const float4*)x)[(long long)row * (IN_FEAT / 4) + kk];
      *(float4*)&xsl[rr * IN_FEAT + ((kk ^ (rr & 7)) << 2)] = v;
    }
    __syncthreads();
    float acc = 0.f;
#pragma unroll 8
    for (int kk = 0; kk < IN_FEAT / 4; kk++) {
      float4 xv = *(const float4*)&xsl[r * IN_FEAT + ((kk ^ xsw) << 2)];
      float4 wv = *(const float4*)&Wt[c * IN_FEAT + ((kk ^ wsw) << 2)];
      acc = fmaf(xv.x, wv.x, acc);
      acc = fmaf(xv.y, wv.y, acc);
      acc = fmaf(xv.z, wv.z, acc);
      acc = fmaf(xv.w, wv.w, acc);
    }
    int row = r0 + r;
    if (row < n) {
      float val = acc * dinv[row];
      hs1[(long long)row * HID + c] = val;
      if (t1) t1[(long long)row * HID + c] = val;
    }
    __syncthreads();
  }
}

__global__ void k_deg_init(float* __restrict__ deg, int n) {
  int i = blockIdx.x * TPB + threadIdx.x;
  if (i < n) deg[i] = 1.0f;
}

__global__ void k_deg_accum(const int* __restrict__ ei32, const long long* __restrict__ ei64,
                            const int* __restrict__ flag, float* __restrict__ deg, int E) {
  int e = blockIdx.x * TPB + threadIdx.x;
  if (e >= E) return;
  int d = (*flag) ? (int)ei64[(long long)E + e] : ei32[(long long)E + e];
  atomicAdd(&deg[d], 1.0f);
}

__global__ void k_rsqrt(float* __restrict__ deg, int n) {
  int i = blockIdx.x * TPB + threadIdx.x;
  if (i < n) deg[i] = rsqrtf(deg[i]);
}

__global__ void k_scatter1(const int* __restrict__ ei32, const long long* __restrict__ ei64,
                           const int* __restrict__ flag, const float* __restrict__ hs1,
                           float* __restrict__ t1, int E) {
  long long gid = (long long)blockIdx.x * TPB + threadIdx.x;
  long long e = gid >> 4;
  if (e >= E) return;
  int f = (int)(gid & 15);
  int s, d;
  if (*flag) {
    s = (int)ei64[e];
    d = (int)ei64[E + e];
  } else {
    s = ei32[e];
    d = ei32[(long long)E + e];
  }
  atomicAdd(&t1[(long long)d * HID + f], hs1[(long long)s * HID + f]);
}

__global__ void k_scatter2(const int* __restrict__ ei32, const long long* __restrict__ ei64,
                           const int* __restrict__ flag, const float* __restrict__ hs2,
                           float* __restrict__ t2, int E) {
  long long gid = (long long)blockIdx.x * TPB + threadIdx.x;
  long long e = gid >> 3;
  if (e >= E) return;
  int f = (int)(gid & 7);
  if (f == 7) return;
  int s, d;
  if (*flag) {
    s = (int)ei64[e];
    d = (int)ei64[E + e];
  } else {
    s = ei32[e];
    d = ei32[(long long)E + e];
  }
  atomicAdd(&t2[(long long)d * 8 + f], hs2[(long long)s * 8 + f]);
}

__global__ void k_final(const float* __restrict__ t2, const float* __restrict__ dinv,
                        const float* __restrict__ b2, float* __restrict__ out, int n) {
  int i = blockIdx.x * TPB + threadIdx.x;
  if (i >= n) return;
  float di = dinv[i];
  float v[7];
  float m = -1e30f;
#pragma unroll
  for (int j = 0; j < 7; j++) {
    v[j] = fmaf(di, t2[(long long)i * 8 + j], b2[j]);
    m = fmaxf(m, v[j]);
  }
  float s = 0.f;
#pragma unroll
  for (int j = 0; j < 7; j++) s += expf(v[j] - m);
  float lse = m + logf(s);
#pragma unroll
  for (int j = 0; j < 7; j++) out[(long long)i * 7 + j] = v[j] - lse;
}

}  // namespace

extern "C" void kernel_launch(void* const* d_in, const int* in_sizes, int n_in,
                              void* d_out, int out_size, void* d_ws, size_t ws_size,
                              hipStream_t stream) {
  const float* x = (const float*)d_in[0];
  const int* ei32 = (const int*)d_in[1];
  const long long* ei64 = (const long long*)d_in[1];
  const float* W1 = (const float*)d_in[2];
  const float* b1 = (const float*)d_in[3];
  const float* W2 = (const float*)d_in[4];
  const float* b2 = (const float*)d_in[5];
  float* out = (float*)d_out;

  int n = in_sizes[0] / IN_FEAT;  // 100000
  int E = in_sizes[1] / 2;        // 3200000

  int nb_n = (n + TPB - 1) / TPB;
  int nb_e = (E + TPB - 1) / TPB;
  int nb_w = (n + 3) / 4;      // wave-per-node kernels
  int nb_g = (n + 191) / 192;  // gemm1b tiles
  int NB = (n + 255) >> 8;     // dst buckets (256 nodes each)
  int NCH = (int)(((long long)E + 8191) / 8192);

  float* ws = (float*)d_ws;
  int* flag = (int*)d_ws;
  auto align16 = [](long long v) { return (v + 15) & ~15LL; };

  // ---- binned-CSR layout ----
  long long w = 64;
  float* dinv = ws + w; w = align16(w + n);
  int* offsets = (int*)(ws + w); w = align16(w + n + 1);
  int* bucketCnt = (int*)(ws + w); w = align16(w + NB);
  int* bucketBase = (int*)(ws + w); w = align16(w + NB + 1);
  int* cursor = (int*)(ws + w); w = align16(w + NB);
  unsigned int* binned = (unsigned int*)(ws + w); w = align16(w + E);
  int* csr = (int*)(ws + w); w = align16(w + E);
  float* hs1 = ws + w; w = align16(w + (long long)n * HID);
  float* t1 = ws + w; w = align16(w + (long long)n * HID);
  float* hs2 = ws + w; w = align16(w + (long long)n * 8);
  bool bin_ok = (NB >= 1) && (NB <= 1024) && (n <= (1 << 24)) &&
                (ws_size >= (size_t)w * 4);

  // ---- legacy CSR layout (fallback #1) ----
  long long w2l = 64;
  float* dinv_c = ws + w2l; w2l = align16(w2l + n);
  int* offsets_c = (int*)(ws + w2l); w2l = align16(w2l + n + 1);
  int* cursor_c = (int*)(ws + w2l); w2l = align16(w2l + n);
  int* csr_c = (int*)(ws + w2l); w2l = align16(w2l + E);
  float* hs1_c = ws + w2l; w2l = align16(w2l + (long long)n * HID);
  float* t1_c = ws + w2l; w2l = align16(w2l + (long long)n * HID);
  float* hs2_c = ws + w2l; w2l = align16(w2l + (long long)n * 8);
  bool csr_ok = (ws_size >= (size_t)w2l * 4);

  if (bin_ok) {
    int nb_nb = (NB + TPB - 1) / TPB;
    hipLaunchKernelGGL(k_detect, dim3(1), dim3(TPB), 0, stream, ei32, flag);
    hipLaunchKernelGGL(k_zero_i, dim3(nb_nb), dim3(TPB), 0, stream, bucketCnt, NB);
    hipLaunchKernelGGL(k_binA, dim3(NCH), dim3(TPB), 0, stream, ei32, ei64, flag, bucketCnt, E, NB);
    hipLaunchKernelGGL(k_binB, dim3(1), dim3(SCANT), 0, stream, bucketCnt, bucketBase, cursor,
                       offsets, n, NB);
    hipLaunchKernelGGL(k_binC, dim3(NCH), dim3(TPB), 0, stream, ei32, ei64, flag, cursor, binned,
                       E, NB);
    hipLaunchKernelGGL(k_binD, dim3(NB), dim3(TPB), 0, stream, bucketBase, binned, offsets, dinv,
                       csr, n);
    hipLaunchKernelGGL(k_gemm1b, dim3(nb_g), dim3(TPB), 0, stream, x, W1, dinv, hs1, n);
    hipLaunchKernelGGL(k_agg1, dim3(nb_w), dim3(TPB), 0, stream, offsets, csr, hs1, t1, n);
    hipLaunchKernelGGL(k_layer2, dim3(nb_n), dim3(TPB), 0, stream, t1, dinv, b1, W2, hs2,
                       (float*)nullptr, n);
    hipLaunchKernelGGL(k_agg2, dim3(nb_w), dim3(TPB), 0, stream, offsets, csr, hs2, dinv, b2,
                       out, n);
  } else if (csr_ok) {
    hipLaunchKernelGGL(k_detect, dim3(1), dim3(TPB), 0, stream, ei32, flag);
    hipLaunchKernelGGL(k_zero_i, dim3(nb_n), dim3(TPB), 0, stream, cursor_c, n);
    hipLaunchKernelGGL(k_hist, dim3(nb_e), dim3(TPB), 0, stream, ei32, ei64, flag, cursor_c, E);
    hipLaunchKernelGGL(k_scan, dim3(1), dim3(SCANT), 0, stream, cursor_c, offsets_c, dinv_c, n);
    hipLaunchKernelGGL(k_build, dim3(nb_e), dim3(TPB), 0, stream, ei32, ei64, flag, cursor_c,
                       csr_c, E);
    hipLaunchKernelGGL(k_gemm1b, dim3(nb_g), dim3(TPB), 0, stream, x, W1, dinv_c, hs1_c, n);
    hipLaunchKernelGGL(k_agg1, dim3(nb_w), dim3(TPB), 0, stream, offsets_c, csr_c, hs1_c, t1_c, n);
    hipLaunchKernelGGL(k_layer2, dim3(nb_n), dim3(TPB), 0, stream, t1_c, dinv_c, b1, W2, hs2_c,
                       (float*)nullptr, n);
    hipLaunchKernelGGL(k_agg2, dim3(nb_w), dim3(TPB), 0, stream, offsets_c, csr_c, hs2_c, dinv_c,
                       b2, out, n);
  } else {
    float* dinv_f = ws + 64;
    float* hs1_f = dinv_f + n;
    float* t1_f = hs1_f + (long long)n * HID;
    float* hs2_f = t1_f + (long long)n * HID;
    float* t2_f = hs2_f + (long long)n * 8;
    long long w1s = (long long)E * 16, w2s = (long long)E * 8;
    int nb_s1 = (int)((w1s + TPB - 1) / TPB);
    int nb_s2 = (int)((w2s + TPB - 1) / TPB);
    hipLaunchKernelGGL(k_detect, dim3(1), dim3(TPB), 0, stream, ei32, flag);
    hipLaunchKernelGGL(k_deg_init, dim3(nb_n), dim3(TPB), 0, stream, dinv_f, n);
    hipLaunchKernelGGL(k_deg_accum, dim3(nb_e), dim3(TPB), 0, stream, ei32, ei64, flag, dinv_f, E);
    hipLaunchKernelGGL(k_rsqrt, dim3(nb_n), dim3(TPB), 0, stream, dinv_f, n);
    hipLaunchKernelGGL(k_gemm1, dim3(1024), dim3(TPB), 0, stream, x, W1, dinv_f, hs1_f, t1_f, n);
    hipLaunchKernelGGL(k_scatter1, dim3(nb_s1), dim3(TPB), 0, stream, ei32, ei64, flag, hs1_f,
                       t1_f, E);
    hipLaunchKernelGGL(k_layer2, dim3(nb_n), dim3(TPB), 0, stream, t1_f, dinv_f, b1, W2, hs2_f,
                       t2_f, n);
    hipLaunchKernelGGL(k_scatter2, dim3(nb_s2), dim3(TPB), 0, stream, ei32, ei64, flag, hs2_f,
                       t2_f, E);
    hipLaunchKernelGGL(k_final, dim3(nb_n), dim3(TPB), 0, stream, t2_f, dinv_f, b2, out, n);
  }
}